// Round 1
// baseline (338.831 us; speedup 1.0000x reference)
//
#include <hip/hip_runtime.h>

#define D_   64
#define NBT_ 12800   // B*T = 32*400
#define B_   32

// Broadcast lane l's value of v to all lanes (SGPR result).
__device__ __forceinline__ float rl(float v, int l) {
    return __uint_as_float(__builtin_amdgcn_readlane(__float_as_uint(v), l));
}

// One wave (64 lanes) per (b,t) matrix. Lane i holds row i of sigma in 64 VGPRs.
// Right-looking Cholesky fully unrolled; column broadcast via v_readlane with
// immediate lane index. Forward substitution (L z = diff) and log-det fused
// into the same column sweep. Upper-triangle registers accumulate garbage but
// are never read through the readlane path (always lane >= current k).
__global__ __launch_bounds__(256) void chol_ll(const float* __restrict__ x,
                                               const float* __restrict__ mu,
                                               const float* __restrict__ sigma,
                                               float* __restrict__ partial) {
    const int lane = threadIdx.x & 63;
    const int wv   = threadIdx.x >> 6;
    const int bt   = blockIdx.x * 4 + wv;

    const float4* srow = (const float4*)(sigma + (size_t)bt * (D_ * D_) + (size_t)lane * D_);
    float row[D_];
    #pragma unroll
    for (int m = 0; m < D_ / 4; ++m) {
        float4 t = srow[m];
        row[4 * m + 0] = t.x; row[4 * m + 1] = t.y;
        row[4 * m + 2] = t.z; row[4 * m + 3] = t.w;
    }
    float d = x[bt * D_ + lane] - mu[bt * D_ + lane];

    float q = 0.f, lg = 0.f;
    #pragma unroll
    for (int k = 0; k < D_; ++k) {
        // diagonal (lane k's row[k] is valid) + EPS regularization
        float s   = rl(row[k], k) + 1e-6f;
        float inv = __builtin_amdgcn_rsqf(s);   // 1/L[k][k]
        lg += __builtin_amdgcn_logf(s);         // log2(s); scaled at end
        row[k] *= inv;                          // L[i][k] for lanes i >= k
        // fused forward substitution: z_k = d_k / L[k][k]
        float zk = rl(d, k) * inv;
        q += zk * zk;
        d -= row[k] * zk;                       // valid for lanes i > k; lanes < k dead
        // rank-1 trailing update: row[j] -= L[i][k] * L[j][k]
        #pragma unroll
        for (int j = k + 1; j < D_; ++j)
            row[j] -= row[k] * rl(row[k], j);   // lane j >= k+1 -> valid broadcast
    }
    if (lane == 0) {
        float log_det = 0.34657359027997264f * lg;      // 0.5 * ln(2) * sum(log2 s)
        // -0.5*sum(z^2) - log_det - 0.5*D*ln(2*pi)
        float lp = -0.5f * q - log_det - 58.81206612509905f;
        partial[bt] = lp;
    }
}

__global__ __launch_bounds__(1024) void reduce_ll(const float* __restrict__ partial,
                                                  float* __restrict__ out) {
    float s = 0.f;
    for (int i = threadIdx.x; i < NBT_; i += 1024) s += partial[i];
    #pragma unroll
    for (int off = 32; off > 0; off >>= 1) s += __shfl_down(s, off, 64);
    __shared__ float ws[16];
    const int lane = threadIdx.x & 63, w = threadIdx.x >> 6;
    if (lane == 0) ws[w] = s;
    __syncthreads();
    if (threadIdx.x == 0) {
        float t = 0.f;
        #pragma unroll
        for (int i = 0; i < 16; ++i) t += ws[i];
        out[0] = -t / (float)B_;   // out = -mean_b sum_t log_prob
    }
}

extern "C" void kernel_launch(void* const* d_in, const int* in_sizes, int n_in,
                              void* d_out, int out_size, void* d_ws, size_t ws_size,
                              hipStream_t stream) {
    const float* x     = (const float*)d_in[0];
    const float* mu    = (const float*)d_in[1];
    const float* sigma = (const float*)d_in[2];
    float* partial = (float*)d_ws;   // NBT_ floats = 51.2 KB scratch
    chol_ll<<<NBT_ / 4, 256, 0, stream>>>(x, mu, sigma, partial);
    reduce_ll<<<1, 1024, 0, stream>>>(partial, (float*)d_out);
}